// Round 5
// baseline (245.878 us; speedup 1.0000x reference)
//
#include <hip/hip_runtime.h>
#include <stdint.h>

#define NPTS 2048
#define KDIM 4096
#define INVALID_KEY 0xFFFFFFFFFFFFFFFFull

typedef __bf16 bf16x8 __attribute__((ext_vector_type(8)));
typedef float f32x4 __attribute__((ext_vector_type(4)));

__device__ __forceinline__ unsigned short f2bf(float f) {
    unsigned int u = __float_as_uint(f);
    u = (u + 0x7FFFu + ((u >> 16) & 1u)) >> 16;   // RNE
    return (unsigned short)u;
}

__device__ __forceinline__ void gld_lds16(const unsigned short* g, unsigned short* l) {
    __builtin_amdgcn_global_load_lds(
        (const __attribute__((address_space(1))) unsigned int*)g,
        (__attribute__((address_space(3))) unsigned int*)l, 16, 0, 0);
}

// key = (d2_bits << 22) | (min(i,j) << 11) | max(i,j): unique per undirected
// edge -> tie-free total order -> hooking cycles are only mutual 2-cycles.
__device__ __forceinline__ unsigned long long mk_key(float w, int i, int j) {
    unsigned long long a = (i < j) ? i : j;
    unsigned long long b = (i < j) ? j : i;
    return ((unsigned long long)__float_as_uint(w) << 22) | (a << 11) | b;
}

// ---- Kernel 1: fp32->bf16 convert + sqnorm + state init ------------------
__global__ __launch_bounds__(256) void convert_sqnorm_kernel(const float* __restrict__ x,
                                                             unsigned short* __restrict__ xb,
                                                             float* __restrict__ sq,
                                                             int* __restrict__ comp0,
                                                             unsigned long long* __restrict__ best0,
                                                             int* __restrict__ ctl) {
    const int row = blockIdx.x;
    const float* xr = x + (size_t)row * KDIM;
    unsigned short* xbr = xb + (size_t)row * KDIM;
    const int t = threadIdx.x;
    float s = 0.f;
    #pragma unroll
    for (int k = 0; k < 4; ++k) {
        int c = t * 4 + k * 1024;
        float4 v = *(const float4*)(xr + c);
        s += v.x * v.x + v.y * v.y + v.z * v.z + v.w * v.w;
        uint2 u;
        u.x = (unsigned)f2bf(v.x) | ((unsigned)f2bf(v.y) << 16);
        u.y = (unsigned)f2bf(v.z) | ((unsigned)f2bf(v.w) << 16);
        *(uint2*)(xbr + c) = u;
    }
    for (int off = 32; off; off >>= 1) s += __shfl_down(s, off);
    __shared__ float p[4];
    if ((t & 63) == 0) p[t >> 6] = s;
    __syncthreads();
    if (t == 0) {
        sq[row] = p[0] + p[1] + p[2] + p[3];
        comp0[row] = row;
        best0[row] = INVALID_KEY;
        if (row == 0) { ctl[0] = 0; ctl[1] = 0; }
    }
}

// ---- Kernel 2: GEMM D2 = sq_i+sq_j-2*XbXb^T, BK=64, fused round-0 scan ---
__global__ __launch_bounds__(256, 2) void gemm_d2_glds(const unsigned short* __restrict__ xb,
                                                       const float* __restrict__ sq,
                                                       float* __restrict__ D2,
                                                       unsigned long long* __restrict__ best0) {
    __shared__ unsigned short As[64 * 64];    // 8 KB
    __shared__ unsigned short Bs[128 * 64];   // 16 KB
    const int I0 = blockIdx.y * 64;
    const int J0 = blockIdx.x * 128;
    const int t = threadIdx.x;
    const int lane = t & 63;
    const int w = t >> 6;
    const int m = lane & 15, q = lane >> 4;

    const unsigned short* gA[2]; unsigned short* lA[2];
    #pragma unroll
    for (int o = 0; o < 2; ++o) {
        int u = o * 256 + t; int rr = u >> 3, cc = u & 7;
        gA[o] = xb + (size_t)(I0 + rr) * KDIM + cc * 8;
        lA[o] = As + (o * 256 + w * 64) * 8;     // wave-uniform base; HW adds lane*16B
    }
    const unsigned short* gB[4]; unsigned short* lB[4];
    #pragma unroll
    for (int o = 0; o < 4; ++o) {
        int u = o * 256 + t; int rr = u >> 3, cc = u & 7;
        gB[o] = xb + (size_t)(J0 + rr) * KDIM + cc * 8;
        lB[o] = Bs + (o * 256 + w * 64) * 8;
    }

    f32x4 acc[4][2] = {};
    for (int kc = 0; kc < KDIM; kc += 64) {
        #pragma unroll
        for (int o = 0; o < 2; ++o) gld_lds16(gA[o] + kc, lA[o]);
        #pragma unroll
        for (int o = 0; o < 4; ++o) gld_lds16(gB[o] + kc, lB[o]);
        __syncthreads();
        #pragma unroll
        for (int ks = 0; ks < 2; ++ks) {
            bf16x8 af[4], bg[2];
            #pragma unroll
            for (int rt = 0; rt < 4; ++rt)
                af[rt] = *(const bf16x8*)(As + (rt * 16 + m) * 64 + ks * 32 + q * 8);
            #pragma unroll
            for (int ct = 0; ct < 2; ++ct)
                bg[ct] = *(const bf16x8*)(Bs + (w * 32 + ct * 16 + m) * 64 + ks * 32 + q * 8);
            #pragma unroll
            for (int rt = 0; rt < 4; ++rt)
                #pragma unroll
                for (int ct = 0; ct < 2; ++ct)
                    acc[rt][ct] = __builtin_amdgcn_mfma_f32_16x16x32_bf16(
                        af[rt], bg[ct], acc[rt][ct], 0, 0, 0);
        }
        __syncthreads();
    }

    // Epilogue: store D2 + fused per-row min-key (round-0 Boruvka scan).
    // C/D: col = lane&15, row = q*4+reg  [m89/m91-verified]
    unsigned long long* s_best = (unsigned long long*)As;   // reuse (post-barrier)
    if (t < 64) s_best[t] = INVALID_KEY;
    __syncthreads();
    #pragma unroll
    for (int rt = 0; rt < 4; ++rt) {
        #pragma unroll
        for (int r = 0; r < 4; ++r) {
            int i = I0 + rt * 16 + q * 4 + r;
            unsigned long long kk = INVALID_KEY;
            #pragma unroll
            for (int ct = 0; ct < 2; ++ct) {
                int j = J0 + w * 32 + ct * 16 + m;
                float v = sq[i] + sq[j] - 2.0f * acc[rt][ct][r];
                v = (i == j) ? __builtin_inff() : fmaxf(v, 0.0f);
                D2[(size_t)i * NPTS + j] = v;
                if (i != j) {
                    unsigned long long key = mk_key(v, i, j);
                    kk = (key < kk) ? key : kk;
                }
            }
            #pragma unroll
            for (int mask = 1; mask < 16; mask <<= 1) {   // butterfly over m (same q)
                unsigned long long o = __shfl_xor(kk, mask);
                kk = (o < kk) ? o : kk;
            }
            if (m == 0) atomicMin(&s_best[rt * 16 + q * 4 + r], kk);
        }
    }
    __syncthreads();
    if (t < 64) atomicMin(&best0[I0 + t], s_best[t]);
}

// ---- Kernel 3: one Boruvka round, single dispatch ------------------------
// Every block redundantly computes the identical deterministic merge in LDS
// (atomicMin order-independent; pointer-jump converges to unique roots), so
// no cross-block communication happens within the dispatch. comp/bestE are
// double-buffered across dispatches (host swaps pointers).
__global__ __launch_bounds__(256) void boruvka_round(const float* __restrict__ D2,
                                                     const unsigned long long* __restrict__ bestP,
                                                     unsigned long long* __restrict__ bestN,
                                                     const int* __restrict__ compP,
                                                     int* __restrict__ compN,
                                                     float* __restrict__ ew,
                                                     int* __restrict__ ctl) {
    if (ctl[1]) return;   // MST complete in an earlier round
    __shared__ int sc[NPTS];                       // 8 KB
    __shared__ int rlist[NPTS];                    // 8 KB (scratch: o(v), then list)
    __shared__ unsigned long long compBest[NPTS];  // 16 KB
    __shared__ int par[NPTS];                      // 8 KB
    __shared__ int s_scan[256];
    __shared__ int s_nroots;
    const int t = threadIdx.x;
    const int bid = blockIdx.x;
    const int lane = t & 63, w = t >> 6;

    if (t == 0) s_nroots = 0;
    #pragma unroll
    for (int e = 0; e < 8; ++e) {
        int v = e * 256 + t;
        sc[v] = compP[v];
        compBest[v] = INVALID_KEY;
    }
    __syncthreads();
    // candidate reduce per component
    #pragma unroll
    for (int e = 0; e < 8; ++e) {
        int v = e * 256 + t;
        unsigned long long k = bestP[v];
        int a = (int)((k >> 11) & 2047), b = (int)(k & 2047);
        int o = (a == v) ? b : a;
        rlist[v] = o;                               // stash other-endpoint
        if (k != INVALID_KEY && sc[o] != sc[v])
            atomicMin(&compBest[sc[v]], k);
    }
    __syncthreads();
    // hook (smaller root survives a mutual 2-cycle); block 0 records weights
    #pragma unroll
    for (int e = 0; e < 8; ++e) {
        int c = e * 256 + t;
        int p = c;
        if (sc[c] == c) {
            unsigned long long k = compBest[c];
            if (k != INVALID_KEY) {
                int a = (int)((k >> 11) & 2047), b = (int)(k & 2047);
                int j = (sc[a] == c) ? b : a;
                int rj = sc[j];
                bool mutual = (compBest[rj] == k);  // keys unique per edge
                if (!(mutual && c < rj)) {
                    p = rj;
                    if (bid == 0)
                        ew[atomicAdd(&ctl[0], 1)] = __uint_as_float((unsigned)(k >> 22));
                }
            }
        }
        par[c] = p;
    }
    __syncthreads();
    for (int it = 0; it < 11; ++it) {
        #pragma unroll
        for (int e = 0; e < 8; ++e) { int c = e * 256 + t; par[c] = par[par[c]]; }
        __syncthreads();
    }
    int newsc[8]; int rc = 0;
    #pragma unroll
    for (int e = 0; e < 8; ++e) {
        int v = e * 256 + t;
        newsc[e] = par[sc[v]];
        if (newsc[e] == v) rc++;
    }
    __syncthreads();
    #pragma unroll
    for (int e = 0; e < 8; ++e) sc[e * 256 + t] = newsc[e];
    if (rc) atomicAdd(&s_nroots, rc);
    __syncthreads();
    const int nroots = s_nroots;
    if (bid == 0) {
        #pragma unroll
        for (int e = 0; e < 8; ++e) compN[e * 256 + t] = newsc[e];
        if (t == 0 && nroots == 1) ctl[1] = 1;
    }
    if (nroots == 1) return;

    // rebuild rescan list (vertices whose cached edge became internal)
    int flags[8], lc = 0;
    #pragma unroll
    for (int e = 0; e < 8; ++e) {
        int v = t * 8 + e;
        int o = rlist[v];
        flags[e] = (sc[o] == sc[v]) ? 1 : 0;
        lc += flags[e];
    }
    s_scan[t] = lc;
    __syncthreads();        // all o(v) reads done before rlist overwrite
    for (int d = 1; d < 256; d <<= 1) {
        int add = (t >= d) ? s_scan[t - d] : 0;
        __syncthreads();
        s_scan[t] += add;
        __syncthreads();
    }
    int base = s_scan[t] - lc;
    #pragma unroll
    for (int e = 0; e < 8; ++e)
        if (flags[e]) rlist[base++] = t * 8 + e;
    __syncthreads();
    const int cnt = s_scan[255];

    // carry-over: block bid owns vertices [bid*4, bid*4+4)
    if (t < 4) {
        int v = bid * 4 + t;
        unsigned long long k = bestP[v];
        int a = (int)((k >> 11) & 2047), b = (int)(k & 2047);
        int o = (a == v) ? b : a;
        if (sc[o] != sc[v]) bestN[v] = k;   // cache still valid: carry over
    }

    // rescan: wave w of block bid handles rlist[bid*4+w]
    int widx = bid * 4 + w;
    if (widx < cnt) {
        int v = rlist[widx];
        int mc = sc[v];
        const float* row = D2 + (size_t)v * NPTS;
        unsigned long long best = INVALID_KEY;
        #pragma unroll
        for (int k = 0; k < 8; ++k) {
            int j0 = k * 256 + lane * 4;
            float4 w4 = *(const float4*)(row + j0);
            int4 c4 = *(const int4*)(sc + j0);
            float wa[4] = {w4.x, w4.y, w4.z, w4.w};
            int ca[4] = {c4.x, c4.y, c4.z, c4.w};
            #pragma unroll
            for (int e = 0; e < 4; ++e) {
                if (ca[e] != mc) {
                    unsigned long long key = mk_key(wa[e], v, j0 + e);
                    best = (key < best) ? key : best;
                }
            }
        }
        for (int off = 32; off; off >>= 1) {
            unsigned long long o = __shfl_down(best, off);
            best = (o < best) ? o : best;
        }
        if (lane == 0) bestN[v] = best;
    }
}

// ---- Kernel 4: sort 2047 weights asc, sqrt, write out --------------------
__global__ __launch_bounds__(1024) void sort_out_kernel(const float* __restrict__ ew,
                                                        float* __restrict__ out) {
    __shared__ float wl[NPTS];
    const int t = threadIdx.x;
    for (int i = t; i < NPTS; i += 1024)
        wl[i] = (i < NPTS - 1) ? ew[i] : __builtin_inff();
    __syncthreads();
    for (int k = 2; k <= NPTS; k <<= 1) {
        for (int j = k >> 1; j > 0; j >>= 1) {
            for (int i = t; i < NPTS; i += 1024) {
                int l = i ^ j;
                if (l > i) {
                    float a = wl[i], b = wl[l];
                    bool up = ((i & k) == 0);
                    if ((a > b) == up) { wl[i] = b; wl[l] = a; }
                }
            }
            __syncthreads();
        }
    }
    for (int i = t; i < NPTS - 1; i += 1024)
        out[i] = sqrtf(fmaxf(wl[i], 0.0f));
}

extern "C" void kernel_launch(void* const* d_in, const int* in_sizes, int n_in,
                              void* d_out, int out_size, void* d_ws, size_t ws_size,
                              hipStream_t stream) {
    const float* x = (const float*)d_in[0];
    float* out = (float*)d_out;
    char* ws = (char*)d_ws;
    unsigned short* xb = (unsigned short*)ws;                          // 16 MB
    float* D2 = (float*)(ws + 16777216);                               // 16 MB
    size_t o = 33554432;
    float* sq = (float*)(ws + o);                  o += 8192;
    unsigned long long* best0 = (unsigned long long*)(ws + o); o += 16384;
    unsigned long long* best1 = (unsigned long long*)(ws + o); o += 16384;
    int* comp0 = (int*)(ws + o);                   o += 8192;
    int* comp1 = (int*)(ws + o);                   o += 8192;
    float* ew = (float*)(ws + o);                  o += 8192;
    int* ctl = (int*)(ws + o);

    hipLaunchKernelGGL(convert_sqnorm_kernel, dim3(NPTS), dim3(256), 0, stream,
                       x, xb, sq, comp0, best0, ctl);
    hipLaunchKernelGGL(gemm_d2_glds, dim3(16, 32), dim3(256), 0, stream,
                       xb, sq, D2, best0);
    for (int r = 0; r < 11; ++r) {
        unsigned long long* bp = (r & 1) ? best1 : best0;
        unsigned long long* bn = (r & 1) ? best0 : best1;
        int* cp = (r & 1) ? comp1 : comp0;
        int* cn = (r & 1) ? comp0 : comp1;
        hipLaunchKernelGGL(boruvka_round, dim3(512), dim3(256), 0, stream,
                           D2, bp, bn, cp, cn, ew, ctl);
    }
    hipLaunchKernelGGL(sort_out_kernel, dim3(1), dim3(1024), 0, stream, ew, out);
}

// Round 6
// 229.036 us; speedup vs baseline: 1.0735x; 1.0735x over previous
//
#include <hip/hip_runtime.h>
#include <stdint.h>

#define NPTS 2048
#define KDIM 4096
#define INVALID_KEY 0xFFFFFFFFFFFFFFFFull

typedef __bf16 bf16x8 __attribute__((ext_vector_type(8)));
typedef float f32x4 __attribute__((ext_vector_type(4)));

__device__ __forceinline__ unsigned short f2bf(float f) {
    unsigned int u = __float_as_uint(f);
    u = (u + 0x7FFFu + ((u >> 16) & 1u)) >> 16;   // RNE
    return (unsigned short)u;
}

__device__ __forceinline__ void gld_lds16(const unsigned short* g, unsigned short* l) {
    __builtin_amdgcn_global_load_lds(
        (const __attribute__((address_space(1))) unsigned int*)g,
        (__attribute__((address_space(3))) unsigned int*)l, 16, 0, 0);
}

// key = (d2_bits << 22) | (min(i,j) << 11) | max(i,j): unique per undirected
// edge -> tie-free total order -> hooking cycles are only mutual 2-cycles.
__device__ __forceinline__ unsigned long long mk_key(float w, int i, int j) {
    unsigned long long a = (i < j) ? i : j;
    unsigned long long b = (i < j) ? j : i;
    return ((unsigned long long)__float_as_uint(w) << 22) | (a << 11) | b;
}

// ---- Kernel 1: fp32->bf16 convert + sqnorm + state init ------------------
__global__ __launch_bounds__(256) void convert_sqnorm_kernel(const float* __restrict__ x,
                                                             unsigned short* __restrict__ xb,
                                                             float* __restrict__ sq,
                                                             int* __restrict__ comp0,
                                                             unsigned long long* __restrict__ best0,
                                                             int* __restrict__ ctl) {
    const int row = blockIdx.x;
    const float* xr = x + (size_t)row * KDIM;
    unsigned short* xbr = xb + (size_t)row * KDIM;
    const int t = threadIdx.x;
    float s = 0.f;
    #pragma unroll
    for (int k = 0; k < 4; ++k) {
        int c = t * 4 + k * 1024;
        float4 v = *(const float4*)(xr + c);
        s += v.x * v.x + v.y * v.y + v.z * v.z + v.w * v.w;
        uint2 u;
        u.x = (unsigned)f2bf(v.x) | ((unsigned)f2bf(v.y) << 16);
        u.y = (unsigned)f2bf(v.z) | ((unsigned)f2bf(v.w) << 16);
        *(uint2*)(xbr + c) = u;
    }
    for (int off = 32; off; off >>= 1) s += __shfl_down(s, off);
    __shared__ float p[4];
    if ((t & 63) == 0) p[t >> 6] = s;
    __syncthreads();
    if (t == 0) {
        sq[row] = p[0] + p[1] + p[2] + p[3];
        comp0[row] = row;
        best0[row] = INVALID_KEY;
        if (row == 0) { ctl[0] = 0; ctl[1] = 0; }
    }
}

// ---- Kernel 2: GEMM D2, BK=32, XOR-swizzled gLDS staging, fused r0 scan --
// 64x128 tile, 12 chunks of 1KB (16 rows x 64B). Staging lane l holds
// (row=l>>2, seg=(l&3)^((l>>3)&3)); reader granule (m, q) sits at
// 32*m + 8*(q^((m>>1)&3)) elems -> bank quads uniform, 2-way (free).
__global__ __launch_bounds__(256, 2) void gemm_d2_glds(const unsigned short* __restrict__ xb,
                                                       const float* __restrict__ sq,
                                                       float* __restrict__ D2,
                                                       unsigned long long* __restrict__ best0) {
    __shared__ __align__(16) unsigned short tile[12 * 512];  // 12 KB: 0-3 A, 4-11 B
    const int I0 = blockIdx.y * 64;
    const int J0 = blockIdx.x * 128;
    const int t = threadIdx.x;
    const int lane = t & 63;
    const int w = t >> 6;
    const int m = lane & 15, q = lane >> 4;

    const int rp = lane >> 2;
    const int sg = (lane & 3) ^ ((lane >> 3) & 3);
    const unsigned short* gsrc[3]; unsigned short* ldst[3];
    #pragma unroll
    for (int ci = 0; ci < 3; ++ci) {
        int c = w * 3 + ci;
        int rowbase = (c < 4) ? (I0 + c * 16) : (J0 + (c - 4) * 16);
        gsrc[ci] = xb + (size_t)(rowbase + rp) * KDIM + sg * 8;
        ldst[ci] = tile + c * 512;          // wave-uniform base; HW adds lane*16B
    }
    const int fro = m * 32 + ((q ^ ((m >> 1) & 3)) * 8);   // swizzled fragment offset

    f32x4 acc[4][2] = {};
    for (int kc = 0; kc < KDIM; kc += 32) {
        #pragma unroll
        for (int ci = 0; ci < 3; ++ci) gld_lds16(gsrc[ci] + kc, ldst[ci]);
        __syncthreads();
        bf16x8 af[4], bg[2];
        #pragma unroll
        for (int rt = 0; rt < 4; ++rt)
            af[rt] = *(const bf16x8*)(tile + rt * 512 + fro);
        #pragma unroll
        for (int ct = 0; ct < 2; ++ct)
            bg[ct] = *(const bf16x8*)(tile + (4 + w * 2 + ct) * 512 + fro);
        #pragma unroll
        for (int rt = 0; rt < 4; ++rt)
            #pragma unroll
            for (int ct = 0; ct < 2; ++ct)
                acc[rt][ct] = __builtin_amdgcn_mfma_f32_16x16x32_bf16(
                    af[rt], bg[ct], acc[rt][ct], 0, 0, 0);
        __syncthreads();
    }

    // Epilogue: store D2 + fused per-row min-key (round-0 scan).
    // C/D: col = lane&15, row = q*4+reg  [m89/m91-verified]
    unsigned long long* s_best = (unsigned long long*)tile;   // reuse post-barrier
    if (t < 64) s_best[t] = INVALID_KEY;
    __syncthreads();
    #pragma unroll
    for (int rt = 0; rt < 4; ++rt) {
        #pragma unroll
        for (int r = 0; r < 4; ++r) {
            int i = I0 + rt * 16 + q * 4 + r;
            unsigned long long kk = INVALID_KEY;
            #pragma unroll
            for (int ct = 0; ct < 2; ++ct) {
                int j = J0 + w * 32 + ct * 16 + m;
                float v = sq[i] + sq[j] - 2.0f * acc[rt][ct][r];
                v = (i == j) ? __builtin_inff() : fmaxf(v, 0.0f);
                D2[(size_t)i * NPTS + j] = v;
                if (i != j) {
                    unsigned long long key = mk_key(v, i, j);
                    kk = (key < kk) ? key : kk;
                }
            }
            #pragma unroll
            for (int mask = 1; mask < 16; mask <<= 1) {   // butterfly over m
                unsigned long long o = __shfl_xor(kk, mask);
                kk = (o < kk) ? o : kk;
            }
            if (m == 0) atomicMin(&s_best[rt * 16 + q * 4 + r], kk);
        }
    }
    __syncthreads();
    if (t < 64) atomicMin(&best0[I0 + t], s_best[t]);
}

// ---- Kernel 3: one Boruvka round (merge redundant per block, fast) -------
__global__ __launch_bounds__(256) void boruvka_round(const float* __restrict__ D2,
                                                     const unsigned long long* __restrict__ bestP,
                                                     unsigned long long* __restrict__ bestN,
                                                     const int* __restrict__ compP,
                                                     int* __restrict__ compN,
                                                     float* __restrict__ ew,
                                                     int* __restrict__ ctl) {
    if (ctl[1]) return;   // MST complete
    __shared__ int sc[NPTS];                       // 8 KB
    __shared__ unsigned long long compBest[NPTS];  // 16 KB
    __shared__ int par[NPTS];                      // 8 KB, reused as rlist
    __shared__ int s_wsum[4];
    __shared__ int s_nroots;
    const int t = threadIdx.x;
    const int bid = blockIdx.x;
    const int lane = t & 63, w = t >> 6;

    if (t == 0) s_nroots = 0;
    #pragma unroll
    for (int e = 0; e < 8; ++e) {
        int v = t * 8 + e;
        sc[v] = compP[v];
        compBest[v] = INVALID_KEY;
    }
    __syncthreads();

    unsigned long long kreg[8]; int oreg[8];
    #pragma unroll
    for (int e = 0; e < 8; ++e) {
        int v = t * 8 + e;
        unsigned long long k = bestP[v];
        kreg[e] = k;
        int a = (int)((k >> 11) & 2047), b = (int)(k & 2047);
        oreg[e] = (a == v) ? b : a;
        if (k != INVALID_KEY && sc[oreg[e]] != sc[v])
            atomicMin(&compBest[sc[v]], k);
    }
    __syncthreads();

    // hook roots (smaller root survives mutual 2-cycle); block 0 records w
    bool isr[8];
    #pragma unroll
    for (int e = 0; e < 8; ++e) {
        int c = t * 8 + e;
        int p = c;
        isr[e] = (sc[c] == c);
        if (isr[e]) {
            unsigned long long k = compBest[c];
            if (k != INVALID_KEY) {
                int a = (int)((k >> 11) & 2047), b = (int)(k & 2047);
                int j = (sc[a] == c) ? b : a;
                int rj = sc[j];
                bool mutual = (compBest[rj] == k);  // keys unique per edge
                if (!(mutual && c < rj)) {
                    p = rj;
                    if (bid == 0)
                        ew[atomicAdd(&ctl[0], 1)] = __uint_as_float((unsigned)(k >> 22));
                }
            }
        }
        par[c] = p;
    }
    // pointer-jump roots until converged (benign races: any read is an ancestor)
    int any = __syncthreads_or(1);   // barrier after par writes
    do {
        int local = 0;
        #pragma unroll
        for (int e = 0; e < 8; ++e) {
            if (isr[e]) {
                int c = t * 8 + e;
                int p = par[c];
                int np = par[p];
                if (np != p) { par[c] = np; local = 1; }
            }
        }
        any = __syncthreads_or(local);
    } while (any);

    int newsc[8]; int rc = 0;
    #pragma unroll
    for (int e = 0; e < 8; ++e) {
        int v = t * 8 + e;
        newsc[e] = par[sc[v]];       // own slot read; par stable
        if (newsc[e] == v) rc++;
    }
    if (rc) atomicAdd(&s_nroots, rc);
    __syncthreads();                 // par reads + nroots adds done
    #pragma unroll
    for (int e = 0; e < 8; ++e) sc[t * 8 + e] = newsc[e];
    __syncthreads();                 // sc visible; par free for reuse
    const int nroots = s_nroots;

    if (bid == 0) {
        #pragma unroll
        for (int e = 0; e < 8; ++e) compN[t * 8 + e] = newsc[e];
        if (t == 0 && nroots == 1) ctl[1] = 1;
    }
    if (nroots == 1) return;

    // rescan list = vertices whose cached edge became internal
    int flags[8], lc = 0;
    #pragma unroll
    for (int e = 0; e < 8; ++e) {
        int v = t * 8 + e;
        flags[e] = (kreg[e] == INVALID_KEY) || (sc[oreg[e]] == sc[v]);
        lc += flags[e];
    }
    int scn = lc;                    // wave inclusive scan
    #pragma unroll
    for (int d = 1; d < 64; d <<= 1) {
        int o = __shfl_up(scn, d);
        if (lane >= d) scn += o;
    }
    if (lane == 63) s_wsum[w] = scn;
    __syncthreads();
    int wbase = 0;
    for (int i = 0; i < w; ++i) wbase += s_wsum[i];
    const int cnt = s_wsum[0] + s_wsum[1] + s_wsum[2] + s_wsum[3];
    int base = wbase + scn - lc;
    int* rlist = par;
    #pragma unroll
    for (int e = 0; e < 8; ++e)
        if (flags[e]) rlist[base++] = t * 8 + e;
    __syncthreads();

    // carry-over still-valid caches: block bid owns vertices [bid*4, bid*4+4)
    if (t < 4) {
        int v = bid * 4 + t;
        unsigned long long k = bestP[v];
        if (k != INVALID_KEY) {
            int a = (int)((k >> 11) & 2047), b = (int)(k & 2047);
            int o = (a == v) ? b : a;
            if (sc[o] != sc[v]) bestN[v] = k;
        }
    }
    // rescan: wave w handles rlist[bid*4 + w]
    int widx = bid * 4 + w;
    if (widx < cnt) {
        int v = rlist[widx];
        int mc = sc[v];
        const float* row = D2 + (size_t)v * NPTS;
        unsigned long long best = INVALID_KEY;
        #pragma unroll
        for (int k = 0; k < 8; ++k) {
            int j0 = k * 256 + lane * 4;
            float4 w4 = *(const float4*)(row + j0);
            int4 c4 = *(const int4*)(sc + j0);
            float wa[4] = {w4.x, w4.y, w4.z, w4.w};
            int ca[4] = {c4.x, c4.y, c4.z, c4.w};
            #pragma unroll
            for (int e = 0; e < 4; ++e) {
                if (ca[e] != mc) {
                    unsigned long long key = mk_key(wa[e], v, j0 + e);
                    best = (key < best) ? key : best;
                }
            }
        }
        for (int off = 32; off; off >>= 1) {
            unsigned long long o = __shfl_down(best, off);
            best = (o < best) ? o : best;
        }
        if (lane == 0) bestN[v] = best;
    }
}

// ---- Kernel 4: sort 2047 weights asc, sqrt, write out --------------------
__global__ __launch_bounds__(1024) void sort_out_kernel(const float* __restrict__ ew,
                                                        float* __restrict__ out) {
    __shared__ float wl[NPTS];
    const int t = threadIdx.x;
    for (int i = t; i < NPTS; i += 1024)
        wl[i] = (i < NPTS - 1) ? ew[i] : __builtin_inff();
    __syncthreads();
    for (int k = 2; k <= NPTS; k <<= 1) {
        for (int j = k >> 1; j > 0; j >>= 1) {
            for (int i = t; i < NPTS; i += 1024) {
                int l = i ^ j;
                if (l > i) {
                    float a = wl[i], b = wl[l];
                    bool up = ((i & k) == 0);
                    if ((a > b) == up) { wl[i] = b; wl[l] = a; }
                }
            }
            __syncthreads();
        }
    }
    for (int i = t; i < NPTS - 1; i += 1024)
        out[i] = sqrtf(fmaxf(wl[i], 0.0f));
}

extern "C" void kernel_launch(void* const* d_in, const int* in_sizes, int n_in,
                              void* d_out, int out_size, void* d_ws, size_t ws_size,
                              hipStream_t stream) {
    const float* x = (const float*)d_in[0];
    float* out = (float*)d_out;
    char* ws = (char*)d_ws;
    unsigned short* xb = (unsigned short*)ws;                          // 16 MB
    float* D2 = (float*)(ws + 16777216);                               // 16 MB
    size_t o = 33554432;
    float* sq = (float*)(ws + o);                  o += 8192;
    unsigned long long* best0 = (unsigned long long*)(ws + o); o += 16384;
    unsigned long long* best1 = (unsigned long long*)(ws + o); o += 16384;
    int* comp0 = (int*)(ws + o);                   o += 8192;
    int* comp1 = (int*)(ws + o);                   o += 8192;
    float* ew = (float*)(ws + o);                  o += 8192;
    int* ctl = (int*)(ws + o);

    hipLaunchKernelGGL(convert_sqnorm_kernel, dim3(NPTS), dim3(256), 0, stream,
                       x, xb, sq, comp0, best0, ctl);
    hipLaunchKernelGGL(gemm_d2_glds, dim3(16, 32), dim3(256), 0, stream,
                       xb, sq, D2, best0);
    for (int r = 0; r < 11; ++r) {
        unsigned long long* bp = (r & 1) ? best1 : best0;
        unsigned long long* bn = (r & 1) ? best0 : best1;
        int* cp = (r & 1) ? comp1 : comp0;
        int* cn = (r & 1) ? comp0 : comp1;
        hipLaunchKernelGGL(boruvka_round, dim3(512), dim3(256), 0, stream,
                           D2, bp, bn, cp, cn, ew, ctl);
    }
    hipLaunchKernelGGL(sort_out_kernel, dim3(1), dim3(1024), 0, stream, ew, out);
}